// Round 9
// baseline (711.926 us; speedup 1.0000x reference)
//
#include <hip/hip_runtime.h>

#define DIM  4096
#define NH   32
#define NKV  8
#define HD   128
#define BSZ  2
#define TSEQ 2048

typedef __bf16 bf16x8 __attribute__((ext_vector_type(8)));
typedef unsigned short ushort8v __attribute__((ext_vector_type(8)));
typedef float f32x4 __attribute__((ext_vector_type(4)));

typedef void GV __attribute__((address_space(1)));
typedef void LV __attribute__((address_space(3)));

__device__ __forceinline__ unsigned short f2bf(float f) {
  unsigned u = __builtin_bit_cast(unsigned, f);
  u += 0x7FFFu + ((u >> 16) & 1u);           // RNE
  return (unsigned short)(u >> 16);
}
__device__ __forceinline__ float bf2f(unsigned short b) {
  unsigned u = ((unsigned)b) << 16;
  return __builtin_bit_cast(float, u);
}
// async global->LDS, 16B per lane. LDS dest is wave-uniform base + lane*16.
__device__ __forceinline__ void gload16(const unsigned short* g, unsigned short* l) {
  __builtin_amdgcn_global_load_lds((GV*)g, (LV*)l, 16, 0, 0);
}
__device__ __forceinline__ f32x4 mfma16(bf16x8 a, bf16x8 b, f32x4 c) {
  return __builtin_amdgcn_mfma_f32_16x16x32_bf16(a, b, c, 0, 0, 0);
}
__device__ __forceinline__ bf16x8 lds8(const unsigned short* p) {
  return __builtin_bit_cast(bf16x8, *(const ushort8v*)p);
}
// dtype probe: freqs_cis[0] word is 0x3F800000 (fp32 cos(0)=1) else bf16 pair
__device__ __forceinline__ int is_bf16(const void* fc) {
  return ((const unsigned int*)fc)[0] != 0x3F800000u;
}

// ---- fused prep: cast x -> bf16 (blocks 0..16383) + 4 weight transposes ----
__global__ __launch_bounds__(256) void prep(const void* __restrict__ x,
                                            const void* __restrict__ fc,
                                            const void* __restrict__ wq,
                                            const void* __restrict__ wk,
                                            const void* __restrict__ wv,
                                            const void* __restrict__ wo,
                                            unsigned short* __restrict__ xb,
                                            unsigned short* __restrict__ wqkvT,
                                            unsigned short* __restrict__ woT) {
  const int isbf = is_bf16(fc);
  const int tid = threadIdx.x;
  int b = (int)blockIdx.x;
  if (b < 16384) {                           // cast x
    long t = (long)b * 256 + tid;
    if (isbf) {
      ((uint2*)xb)[t] = ((const uint2*)x)[t];
    } else {
      float4 f = ((const float4*)x)[t];
      ushort4 o;
      o.x = f2bf(f.x); o.y = f2bf(f.y); o.z = f2bf(f.z); o.w = f2bf(f.w);
      ((ushort4*)xb)[t] = o;
    }
    return;
  }
  // transpose 64x64 tile: src (4096 x C) -> dst (C x 4096) bf16
  __shared__ unsigned short tile[64][68];    // stride 136 B
  b -= 16384;
  const void* src; unsigned short* dst; int C, bx, by;
  if (b < 4096)      { src = wq; dst = wqkvT;                C = 4096; bx = b & 63; by = b >> 6; }
  else if (b < 5120) { b -= 4096; src = wk; dst = wqkvT + 4096L * 4096; C = 1024; bx = b & 15; by = b >> 4; }
  else if (b < 6144) { b -= 5120; src = wv; dst = wqkvT + 5120L * 4096; C = 1024; bx = b & 15; by = b >> 4; }
  else               { b -= 6144; src = wo; dst = woT;       C = 4096; bx = b & 63; by = b >> 6; }
  const int R = 4096;
  const int c0g = bx * 64, r0g = by * 64;
  const int cc = (tid & 15) * 4;
  if (isbf) {
    const unsigned short* s = (const unsigned short*)src;
#pragma unroll
    for (int it = 0; it < 4; ++it) {
      const int r = it * 16 + (tid >> 4);
      ushort4 v = *(const ushort4*)(s + (long)(r0g + r) * C + c0g + cc);
      *(ushort4*)&tile[r][cc] = v;
    }
  } else {
    const float* s = (const float*)src;
#pragma unroll
    for (int it = 0; it < 4; ++it) {
      const int r = it * 16 + (tid >> 4);
      float4 f = *(const float4*)(s + (long)(r0g + r) * C + c0g + cc);
      ushort4 v;
      v.x = f2bf(f.x); v.y = f2bf(f.y); v.z = f2bf(f.z); v.w = f2bf(f.w);
      *(ushort4*)&tile[r][cc] = v;
    }
  }
  __syncthreads();
#pragma unroll
  for (int it = 0; it < 2; ++it) {
    const int c = (tid >> 3) + it * 32;
    const int r0 = (tid & 7) * 8;
    ushort8v o;
#pragma unroll
    for (int u = 0; u < 8; ++u) o[u] = tile[r0 + u][c];
    *(ushort8v*)(dst + (long)(c0g + c) * R + r0g + r0) = o;
  }
}

// =====================================================================================
// 128x128 tile, BK=64, 4 waves (2M x 2N, wave 64x64), 64 KiB LDS => 2 blocks/CU,
// READ-AHEAD: tile t+1's 16 ds_read_b128 are issued in tile t's half2 (after
// vmcnt(6)+BAR prove t+1 landed chip-wide), consumed at tile t+1's lgkmcnt(0) —
// the read burst hides under the kk1 MFMA cluster + stgA1 + barrier.
// Per tile t (slot s=t&1):
//   half1: stgA1[t+1]->s^1; lgkm(0) [frags pre-read]; MFMA kk0; [midBAR: slot-s
//          reads retired by all waves]
//   half2: stgB0,B1,A0[t+2]->s; vmcnt(6) [FIFO: drains A1[t+1], tile t+1 complete];
//          [BAR: visible chip-wide]; read16[t+1] from s^1; MFMA kk1
// Registers: 2 frag sets (128) + acc (64) fits the 256-VGPR cap of (256,2).
// =====================================================================================
__device__ __forceinline__ void gemm128_loop(const unsigned short* __restrict__ A,
                                             const unsigned short* __restrict__ Bt,
                                             unsigned short* As, unsigned short* Bs,
                                             long tileM, long tileN, f32x4 (&acc)[4][4]) {
  const int tid = (int)threadIdx.x;
  const int lane = tid & 63, wave = tid >> 6;
  const int wr = wave >> 1, wc = wave & 1;
  const int lm = lane & 15, quad = lane >> 4;
  const int sr = tid >> 3;
  const int schunk = ((tid & 7) ^ (sr & 7)) * 8;
  const unsigned short* Ag = A + (tileM + sr) * 4096L + schunk;
  const unsigned short* Bg = Bt + (tileN + sr) * 4096L + schunk;
  unsigned short* Al = As + sr * 64 + (tid & 7) * 8;
  unsigned short* Bl = Bs + sr * 64 + (tid & 7) * 8;

  auto stgA = [&](int slot, int half, int tt) {   // half-unit = 64 rows = 2 gloads
    const unsigned short* g = Ag + (long)half * (64 * 4096L) + (long)tt * 64;
    unsigned short* l = Al + slot * 8192 + half * 4096;
    gload16(g, l);
    gload16(g + 32 * 4096L, l + 2048);
  };
  auto stgB = [&](int slot, int half, int tt) {
    const unsigned short* g = Bg + (long)half * (64 * 4096L) + (long)tt * 64;
    unsigned short* l = Bl + slot * 8192 + half * 4096;
    gload16(g, l);
    gload16(g + 32 * 4096L, l + 2048);
  };
  auto rdA = [&](int so, int f, int kk) {
    return lds8(&As[so + (wr * 64 + f * 16 + lm) * 64 + (((kk * 4 + quad) ^ (lm & 7)) * 8)]);
  };
  auto rdB = [&](int so, int f, int kk) {
    return lds8(&Bs[so + (wc * 64 + f * 16 + lm) * 64 + (((kk * 4 + quad) ^ (lm & 7)) * 8)]);
  };

  // prologue: FIFO = steady-state order: tile0 {B0,B1,A0,A1}; tile1 {B0,B1,A0}
  stgB(0, 0, 0); stgB(0, 1, 0); stgA(0, 0, 0); stgA(0, 1, 0);
  stgB(1, 0, 1); stgB(1, 1, 1); stgA(1, 0, 1);
  asm volatile("s_waitcnt vmcnt(6)" ::: "memory");   // tile0 landed
  __builtin_amdgcn_sched_barrier(0);
  __builtin_amdgcn_s_barrier();

  bf16x8 aX[4][2], bX[4][2], aY[4][2], bY[4][2];
#pragma unroll
  for (int f = 0; f < 4; ++f) {
    aX[f][0] = rdA(0, f, 0); aX[f][1] = rdA(0, f, 1);
    bX[f][0] = rdB(0, f, 0); bX[f][1] = rdB(0, f, 1);
  }

  auto tile_body = [&](int t, bf16x8 (&CA)[4][2], bf16x8 (&CB)[4][2],
                       bf16x8 (&NA)[4][2], bf16x8 (&NB)[4][2]) {
    const int s = t & 1;
    const int so = s * 8192, sn = so ^ 8192;
    // ---- half 1 ----
    if (t < 63) stgA(s ^ 1, 1, t + 1);
    asm volatile("s_waitcnt lgkmcnt(0)" ::: "memory");
    __builtin_amdgcn_sched_barrier(0);
    __builtin_amdgcn_s_setprio(1);
#pragma unroll
    for (int mf = 0; mf < 4; ++mf)
#pragma unroll
      for (int nf = 0; nf < 4; ++nf)
        acc[mf][nf] = mfma16(CA[mf][0], CB[nf][0], acc[mf][nf]);
    __builtin_amdgcn_s_setprio(0);
    __builtin_amdgcn_sched_barrier(0);
    __builtin_amdgcn_s_barrier();        // all waves' slot-s reads retired
    // ---- half 2 ----
    if (t < 62) { stgB(s, 0, t + 2); stgB(s, 1, t + 2); stgA(s, 0, t + 2); }
    if (t < 62)       asm volatile("s_waitcnt vmcnt(6)" ::: "memory");
    else if (t == 62) asm volatile("s_waitcnt vmcnt(0)" ::: "memory");
    __builtin_amdgcn_sched_barrier(0);
    __builtin_amdgcn_s_barrier();        // tile t+1 visible chip-wide
    if (t < 63) {
#pragma unroll
      for (int f = 0; f < 4; ++f) {
        NA[f][0] = rdA(sn, f, 0); NA[f][1] = rdA(sn, f, 1);
        NB[f][0] = rdB(sn, f, 0); NB[f][1] = rdB(sn, f, 1);
      }
    }
    __builtin_amdgcn_s_setprio(1);
#pragma unroll
    for (int mf = 0; mf < 4; ++mf)
#pragma unroll
      for (int nf = 0; nf < 4; ++nf)
        acc[mf][nf] = mfma16(CA[mf][1], CB[nf][1], acc[mf][nf]);
    __builtin_amdgcn_s_setprio(0);
  };

  for (int tt = 0; tt < 64; tt += 2) {
    tile_body(tt,     aX, bX, aY, bY);
    tile_body(tt + 1, aY, bY, aX, bX);
  }
}

// ---- fused QKV GEMM + RoPE + layout scatter. XCD-region remap (verified R6). ----
__global__ __launch_bounds__(256, 2) void gemm_qkv8(const unsigned short* __restrict__ A,
                                                    const unsigned short* __restrict__ Bt,
                                                    const void* __restrict__ fcv,
                                                    unsigned short* __restrict__ qo,
                                                    unsigned short* __restrict__ ko,
                                                    unsigned short* __restrict__ vo) {
  __shared__ __align__(16) unsigned short As[2 * 8192];
  __shared__ __align__(16) unsigned short Bs[2 * 8192];
  const int bid = (int)blockIdx.x;                 // 1536 blocks
  const int xcd = bid & 7, idx = bid >> 3;         // idx 0..191
  const int band = idx >> 6;                       // 0..2
  const int rr = idx & 63;                         // 8x8 generation
  const long tileM = (long)((xcd & 3) * 8 + (rr & 7)) * 128;
  const long tileN = (long)((xcd >> 2) * 24 + band * 8 + (rr >> 3)) * 128;
  f32x4 acc[4][4] = {};
  gemm128_loop(A, Bt, As, Bs, tileM, tileN, acc);
  // ---- epilogue: rope + scatter ----
  const int tid = (int)threadIdx.x;
  const int lane = tid & 63, wave = tid >> 6;
  const int wr = wave >> 1, wc = wave & 1;
  const int lm = lane & 15, quad = lane >> 4;
  const int isbf = is_bf16(fcv);
  const int nb = (int)tileN + wc * 64;             // 64-aligned; region uniform per wave
  if (nb < 5120) {                                 // q or k: rope
    const int isk = (nb >= 4096);
    unsigned short* dst = isk ? ko : qo;
    const int hpb = isk ? NKV : NH;
    const int coff = isk ? 4096 : 0;
    const float qs = isk ? 1.0f : 0.08838834764831845f;  // fold softmax scale into q
#pragma unroll
    for (int mf = 0; mf < 4; ++mf)
#pragma unroll
      for (int r = 0; r < 4; ++r) {
        const int m = (int)tileM + wr * 64 + mf * 16 + quad * 4 + r;
        const int b = m >> 11, tq = m & (TSEQ - 1);
#pragma unroll
        for (int nf = 0; nf < 4; ++nf) {
          const int n = nb + nf * 16 + lm;
          float val = acc[mf][nf][r];
          float par = __shfl_xor(val, 1);
          const int ip = (n & 127) >> 1;
          const long fo = (long)tq * 64 + ip;
          float cz, sz;
          if (isbf) {
            const unsigned short* fu = (const unsigned short*)fcv;
            cz = bf2f(fu[fo * 2]); sz = bf2f(fu[fo * 2 + 1]);
          } else {
            float2 cs = ((const float2*)fcv)[fo];
            cz = cs.x; sz = cs.y;
          }
          float out = (n & 1) ? (val * cz + par * sz) : (val * cz - par * sz);
          const int h = (n - coff) >> 7, d = n & 127;
          dst[((long)(b * hpb + h) * TSEQ + tq) * HD + d] = f2bf(out * qs);
        }
      }
  } else {                                         // v: transposed store vT[(b,kvh,d),t]
#pragma unroll
    for (int mf = 0; mf < 4; ++mf)
#pragma unroll
      for (int r = 0; r < 4; ++r) {
        const int m = (int)tileM + wr * 64 + mf * 16 + quad * 4 + r;
        const int b = m >> 11, tq = m & (TSEQ - 1);
#pragma unroll
        for (int nf = 0; nf < 4; ++nf) {
          const int n = nb + nf * 16 + lm;
          const int h = (n - 5120) >> 7, d = n & 127;
          vo[((long)(b * NKV + h) * HD + d) * TSEQ + tq] = f2bf(acc[mf][nf][r]);
        }
      }
  }
}

// ---- wo GEMM: C(4096x4096) = A * Bt^T. XCD region 8M x 16N, 8x8 generations. ----
__global__ __launch_bounds__(256, 2) void gemm_wo8(const unsigned short* __restrict__ A,
                                                   const unsigned short* __restrict__ Bt,
                                                   void* __restrict__ Cv,
                                                   const void* __restrict__ fcv) {
  __shared__ __align__(16) unsigned short As[2 * 8192];
  __shared__ __align__(16) unsigned short Bs[2 * 8192];
  const int bid = (int)blockIdx.x;                 // 1024 blocks
  const int xcd = bid & 7, idx = bid >> 3;         // idx 0..127
  const int band = idx >> 6;                       // 0..1
  const int rr = idx & 63;
  const long tileM = (long)((xcd & 3) * 8 + (rr & 7)) * 128;
  const long tileN = (long)((xcd >> 2) * 16 + band * 8 + (rr >> 3)) * 128;
  f32x4 acc[4][4] = {};
  gemm128_loop(A, Bt, As, Bs, tileM, tileN, acc);
  const int tid = (int)threadIdx.x;
  const int lane = tid & 63, wave = tid >> 6;
  const int wr = wave >> 1, wc = wave & 1;
  const int lm = lane & 15, quad = lane >> 4;
  const int obf = is_bf16(fcv);
  const long N = 4096;
  if (obf) {
    unsigned short* C = (unsigned short*)Cv;
#pragma unroll
    for (int mf = 0; mf < 4; ++mf)
#pragma unroll
      for (int nf = 0; nf < 4; ++nf)
#pragma unroll
        for (int r = 0; r < 4; ++r)
          C[(tileM + wr * 64 + mf * 16 + quad * 4 + r) * N + tileN + wc * 64 + nf * 16 + lm] =
              f2bf(acc[mf][nf][r]);
  } else {
    float* C = (float*)Cv;
#pragma unroll
    for (int mf = 0; mf < 4; ++mf)
#pragma unroll
      for (int nf = 0; nf < 4; ++nf)
#pragma unroll
        for (int r = 0; r < 4; ++r)
          C[(tileM + wr * 64 + mf * 16 + quad * 4 + r) * N + tileN + wc * 64 + nf * 16 + lm] =
              acc[mf][nf][r];
  }
}

// ---- flash attention v5: R8 structure with TRIPLE-buffered K/V => ONE barrier/tile.
// Per tile kt (slot s=kt%3): compute(s) [skipped past diagonal]; stage(kt+2 ->
// (kt+2)%3) [that slot's last reads were tile kt-1, retired before kt-1's barrier];
// vmcnt(2) [drains tile kt+1]; BAR [kt+1 visible chip-wide]. 512 threads, 256
// q/block, heavy half first. Softmax scale pre-folded into q.
__global__ __launch_bounds__(512, 2) void flash_attn(const unsigned short* __restrict__ q,
                                                     const unsigned short* __restrict__ k,
                                                     const unsigned short* __restrict__ vT,
                                                     unsigned short* __restrict__ y) {
  __shared__ unsigned short Ks[3][32 * 128];   // (key, d), chunk-swizzled
  __shared__ unsigned short Vs[3][128 * 32];   // (d, key), chunk-swizzled
  __shared__ unsigned short Pl[8][32 * 40];    // per-wave P (32q x 32k), stride 40
  const int tid = threadIdx.x;
  const int lane = tid & 63, wave = tid >> 6;  // 8 waves
  const int lm = lane & 15, quad = lane >> 4;
  const int bid = (int)blockIdx.x;
  const int halfg = bid >> 8, jj = bid & 255;
  const int qt = jj >> 6, bh = jj & 63;
  const int qi = halfg ? qt : 7 - qt;          // heavy half first
  const int b = bh >> 5, h = bh & 31, kvh = h >> 2;
  const int q0 = qi * 256;
  const unsigned short* Kb = k + (long)(b * NKV + kvh) * TSEQ * HD;
  const unsigned short* Vb = vT + (long)(b * NKV + kvh) * HD * TSEQ;
  const unsigned short* Qb = q + ((long)(b * NH + h) * TSEQ + q0 + wave * 32) * HD;
  bf16x8 qf[2][4];
#pragma unroll
  for (int mi = 0; mi < 2; ++mi)
#pragma unroll
    for (int ks = 0; ks < 4; ++ks)
      qf[mi][ks] = __builtin_bit_cast(bf16x8,
          *(const ushort8v*)(Qb + (mi * 16 + lm) * HD + ks * 32 + quad * 8));
  f32x4 o[2][8] = {};
  float li[2][4] = {};
  const int krow = tid >> 4, kcl = ((tid & 15) ^ (krow & 7)) * 8;       // krow 0..31
  const int vrow = tid >> 2, vcl = ((tid & 3) ^ ((vrow >> 1) & 3)) * 8; // vrow 0..127
  const int ktiles = qi * 8 + 8;
  const int mylast = qi * 8 + wave;            // this wave's diagonal k-tile
  unsigned short* PlW = &Pl[wave][0];

  auto stage = [&](int s2, int t2) {
    gload16(Kb + (long)t2 * 32 * HD + krow * HD + kcl, &Ks[s2][tid * 8]);
    gload16(Vb + t2 * 32 + (long)vrow * TSEQ + vcl, &Vs[s2][tid * 8]);
  };
  // prologue: stage tiles 0,1; drain tile 0 (4 outstanding -> vmcnt(2))
  stage(0, 0); stage(1, 1);
  asm volatile("s_waitcnt vmcnt(2)" ::: "memory");
  __builtin_amdgcn_sched_barrier(0);
  __builtin_amdgcn_s_barrier();

  for (int kt = 0; kt < ktiles; ++kt) {
    const int s = kt % 3;
    if (kt <= mylast) {
      const unsigned short* KsB = Ks[s];
      const unsigned short* VsB = Vs[s];
      f32x4 sc[2][2] = {};
      __builtin_amdgcn_s_setprio(1);
#pragma unroll
      for (int ni = 0; ni < 2; ++ni)
#pragma unroll
        for (int ks = 0; ks < 4; ++ks) {
          bf16x8 kf = lds8(&KsB[(ni * 16 + lm) * 128 + ((ks * 4 + quad) ^ (lm & 7)) * 8]);
          sc[0][ni] = mfma16(qf[0][ks], kf, sc[0][ni]);
          sc[1][ni] = mfma16(qf[1][ks], kf, sc[1][ni]);
        }
      __builtin_amdgcn_s_setprio(0);
      if (kt < mylast) {                       // full tile: no causal compare
#pragma unroll
        for (int mi = 0; mi < 2; ++mi)
#pragma unroll
          for (int r = 0; r < 4; ++r)
#pragma unroll
            for (int ni = 0; ni < 2; ++ni) {
              float p = __expf(sc[mi][ni][r]);
              li[mi][r] += p;
              PlW[(mi * 16 + quad * 4 + r) * 40 + ni * 16 + lm] = f2bf(p);
            }
      } else {                                 // diagonal tile: mask col<=row
#pragma unroll
        for (int mi = 0; mi < 2; ++mi)
#pragma unroll
          for (int r = 0; r < 4; ++r) {
            const int rowo = mi * 16 + quad * 4 + r;
#pragma unroll
            for (int ni = 0; ni < 2; ++ni) {
              const int colo = ni * 16 + lm;
              float p = (colo <= rowo) ? __expf(sc[mi][ni][r]) : 0.f;
              li[mi][r] += p;
              PlW[rowo * 40 + colo] = f2bf(p);
            }
          }
      }
      bf16x8 pf0 = lds8(&PlW[lm * 40 + quad * 8]);
      bf16x8 pf1 = lds8(&PlW[(16 + lm) * 40 + quad * 8]);
      __builtin_amdgcn_s_setprio(1);
#pragma unroll
      for (int db = 0; db < 8; ++db) {
        bf16x8 vf = lds8(&VsB[(db * 16 + lm) * 32 + (quad ^ ((lm >> 1) & 3)) * 8]);
        o[0][db] = mfma16(pf0, vf, o[0][db]);
        o[1][db] = mfma16(pf1, vf, o[1][db]);
      }
      __builtin_amdgcn_s_setprio(0);
    }
    __builtin_amdgcn_sched_barrier(0);
    if (kt + 2 < ktiles) {
      stage((kt + 2) % 3, kt + 2);           // slot last read at tile kt-1
      asm volatile("s_waitcnt vmcnt(2)" ::: "memory");   // tile kt+1 landed
    } else if (kt + 1 < ktiles) {
      asm volatile("s_waitcnt vmcnt(0)" ::: "memory");
    }
    __builtin_amdgcn_sched_barrier(0);
    __builtin_amdgcn_s_barrier();            // single barrier per tile
  }
  float inv[2][4];
#pragma unroll
  for (int mi = 0; mi < 2; ++mi)
#pragma unroll
    for (int r = 0; r < 4; ++r) {
      float l = li[mi][r];
      l += __shfl_xor(l, 1, 16);
      l += __shfl_xor(l, 2, 16);
      l += __shfl_xor(l, 4, 16);
      l += __shfl_xor(l, 8, 16);
      inv[mi][r] = 1.0f / l;
    }
  unsigned short* yo = y + ((long)b * TSEQ + q0 + wave * 32) * DIM + h * 128 + lm;
#pragma unroll
  for (int mi = 0; mi < 2; ++mi)
#pragma unroll
    for (int r = 0; r < 4; ++r) {
      unsigned short* yr = yo + (long)(mi * 16 + quad * 4 + r) * DIM;
#pragma unroll
      for (int db = 0; db < 8; ++db)
        yr[db * 16] = f2bf(o[mi][db][r] * inv[mi][r]);
    }
}

extern "C" void kernel_launch(void* const* d_in, const int* in_sizes, int n_in,
                              void* d_out, int out_size, void* d_ws, size_t ws_size,
                              hipStream_t stream) {
  const void* x  = d_in[0];
  const void* fc = d_in[1];
  const void* wq = d_in[2];
  const void* wk = d_in[3];
  const void* wv = d_in[4];
  const void* wo = d_in[5];
  char* ws = (char*)d_ws;
  unsigned short* xb    = (unsigned short*)(ws + 256);      // 16,777,216 elems (reused as y)
  unsigned short* wqkvT = xb + 16777216L;                   // 25,165,824 elems
  unsigned short* woT   = wqkvT + 25165824L;                // 16,777,216 elems
  unsigned short* qb    = woT + 16777216L;                  // 16,777,216 elems
  unsigned short* kb    = qb + 16777216L;                   //  4,194,304 elems
  unsigned short* vb    = kb + 4194304L;                    //  4,194,304 elems
  unsigned short* yb    = xb;

  prep<<<dim3(26624), dim3(256), 0, stream>>>(x, fc, wq, wk, wv, wo, xb, wqkvT, woT);
  gemm_qkv8<<<dim3(1536), dim3(256), 0, stream>>>(xb, wqkvT, fc, qb, kb, vb);
  flash_attn<<<dim3(512), dim3(512), 0, stream>>>(qb, kb, vb, yb);
  gemm_wo8<<<dim3(1024), dim3(256), 0, stream>>>(yb, woT, d_out, fc);
}

// Round 10
// 683.271 us; speedup vs baseline: 1.0419x; 1.0419x over previous
//
#include <hip/hip_runtime.h>

#define DIM  4096
#define NH   32
#define NKV  8
#define HD   128
#define BSZ  2
#define TSEQ 2048

typedef __bf16 bf16x8 __attribute__((ext_vector_type(8)));
typedef unsigned short ushort8v __attribute__((ext_vector_type(8)));
typedef float f32x4 __attribute__((ext_vector_type(4)));

typedef void GV __attribute__((address_space(1)));
typedef void LV __attribute__((address_space(3)));

__device__ __forceinline__ unsigned short f2bf(float f) {
  unsigned u = __builtin_bit_cast(unsigned, f);
  u += 0x7FFFu + ((u >> 16) & 1u);           // RNE
  return (unsigned short)(u >> 16);
}
__device__ __forceinline__ float bf2f(unsigned short b) {
  unsigned u = ((unsigned)b) << 16;
  return __builtin_bit_cast(float, u);
}
// async global->LDS, 16B per lane. LDS dest is wave-uniform base + lane*16.
__device__ __forceinline__ void gload16(const unsigned short* g, unsigned short* l) {
  __builtin_amdgcn_global_load_lds((GV*)g, (LV*)l, 16, 0, 0);
}
__device__ __forceinline__ f32x4 mfma16(bf16x8 a, bf16x8 b, f32x4 c) {
  return __builtin_amdgcn_mfma_f32_16x16x32_bf16(a, b, c, 0, 0, 0);
}
__device__ __forceinline__ bf16x8 lds8(const unsigned short* p) {
  return __builtin_bit_cast(bf16x8, *(const ushort8v*)p);
}
// dtype probe: freqs_cis[0] word is 0x3F800000 (fp32 cos(0)=1) else bf16 pair
__device__ __forceinline__ int is_bf16(const void* fc) {
  return ((const unsigned int*)fc)[0] != 0x3F800000u;
}

// ---- fused prep: cast x -> bf16 (blocks 0..16383) + 4 weight transposes ----
__global__ __launch_bounds__(256) void prep(const void* __restrict__ x,
                                            const void* __restrict__ fc,
                                            const void* __restrict__ wq,
                                            const void* __restrict__ wk,
                                            const void* __restrict__ wv,
                                            const void* __restrict__ wo,
                                            unsigned short* __restrict__ xb,
                                            unsigned short* __restrict__ wqkvT,
                                            unsigned short* __restrict__ woT) {
  const int isbf = is_bf16(fc);
  const int tid = threadIdx.x;
  int b = (int)blockIdx.x;
  if (b < 16384) {                           // cast x
    long t = (long)b * 256 + tid;
    if (isbf) {
      ((uint2*)xb)[t] = ((const uint2*)x)[t];
    } else {
      float4 f = ((const float4*)x)[t];
      ushort4 o;
      o.x = f2bf(f.x); o.y = f2bf(f.y); o.z = f2bf(f.z); o.w = f2bf(f.w);
      ((ushort4*)xb)[t] = o;
    }
    return;
  }
  // transpose 64x64 tile: src (4096 x C) -> dst (C x 4096) bf16
  __shared__ unsigned short tile[64][68];    // stride 136 B
  b -= 16384;
  const void* src; unsigned short* dst; int C, bx, by;
  if (b < 4096)      { src = wq; dst = wqkvT;                C = 4096; bx = b & 63; by = b >> 6; }
  else if (b < 5120) { b -= 4096; src = wk; dst = wqkvT + 4096L * 4096; C = 1024; bx = b & 15; by = b >> 4; }
  else if (b < 6144) { b -= 5120; src = wv; dst = wqkvT + 5120L * 4096; C = 1024; bx = b & 15; by = b >> 4; }
  else               { b -= 6144; src = wo; dst = woT;       C = 4096; bx = b & 63; by = b >> 6; }
  const int R = 4096;
  const int c0g = bx * 64, r0g = by * 64;
  const int cc = (tid & 15) * 4;
  if (isbf) {
    const unsigned short* s = (const unsigned short*)src;
#pragma unroll
    for (int it = 0; it < 4; ++it) {
      const int r = it * 16 + (tid >> 4);
      ushort4 v = *(const ushort4*)(s + (long)(r0g + r) * C + c0g + cc);
      *(ushort4*)&tile[r][cc] = v;
    }
  } else {
    const float* s = (const float*)src;
#pragma unroll
    for (int it = 0; it < 4; ++it) {
      const int r = it * 16 + (tid >> 4);
      float4 f = *(const float4*)(s + (long)(r0g + r) * C + c0g + cc);
      ushort4 v;
      v.x = f2bf(f.x); v.y = f2bf(f.y); v.z = f2bf(f.z); v.w = f2bf(f.w);
      *(ushort4*)&tile[r][cc] = v;
    }
  }
  __syncthreads();
#pragma unroll
  for (int it = 0; it < 2; ++it) {
    const int c = (tid >> 3) + it * 32;
    const int r0 = (tid & 7) * 8;
    ushort8v o;
#pragma unroll
    for (int u = 0; u < 8; ++u) o[u] = tile[r0 + u][c];
    *(ushort8v*)(dst + (long)(c0g + c) * R + r0g + r0) = o;
  }
}

// =====================================================================================
// 128x128 tile, BK=64, 4 waves (2M x 2N, wave 64x64), 64 KiB LDS => 2 blocks/CU.
// R8 min-sync schedule + SPLIT lgkm wait: ds reads issued in pinned order
// {kk0 x8, kk1 x8}; lgkmcnt(8) releases MFMA kk0 while the kk1 reads retire under
// it; lgkmcnt(0) after kk0 (before the mid barrier) guarantees all slot-s reads
// retired before half2 stages into s. FIFO/vmcnt accounting identical to R8:
//   half1: reads + stgA1[t+1]->s^1; lgkm(8); MFMA kk0; lgkm(0); [BAR]
//   half2: stgB0,B1,A0[t+2]->s; MFMA kk1; vmcnt(6); [BAR]
// vmcnt(6) drains through A1[t+1] (oldest of 8 outstanding) => tile t+1 landed.
// =====================================================================================
__device__ __forceinline__ void gemm128_loop(const unsigned short* __restrict__ A,
                                             const unsigned short* __restrict__ Bt,
                                             unsigned short* As, unsigned short* Bs,
                                             long tileM, long tileN, f32x4 (&acc)[4][4]) {
  const int tid = (int)threadIdx.x;
  const int lane = tid & 63, wave = tid >> 6;
  const int wr = wave >> 1, wc = wave & 1;
  const int lm = lane & 15, quad = lane >> 4;
  const int sr = tid >> 3;
  const int schunk = ((tid & 7) ^ (sr & 7)) * 8;
  const unsigned short* Ag = A + (tileM + sr) * 4096L + schunk;
  const unsigned short* Bg = Bt + (tileN + sr) * 4096L + schunk;
  unsigned short* Al = As + sr * 64 + (tid & 7) * 8;
  unsigned short* Bl = Bs + sr * 64 + (tid & 7) * 8;

  auto stgA = [&](int slot, int half, int tt) {   // half-unit = 64 rows = 2 gloads
    const unsigned short* g = Ag + (long)half * (64 * 4096L) + (long)tt * 64;
    unsigned short* l = Al + slot * 8192 + half * 4096;
    gload16(g, l);
    gload16(g + 32 * 4096L, l + 2048);
  };
  auto stgB = [&](int slot, int half, int tt) {
    const unsigned short* g = Bg + (long)half * (64 * 4096L) + (long)tt * 64;
    unsigned short* l = Bl + slot * 8192 + half * 4096;
    gload16(g, l);
    gload16(g + 32 * 4096L, l + 2048);
  };
  auto rdA = [&](int so, int f, int kk) {
    return lds8(&As[so + (wr * 64 + f * 16 + lm) * 64 + (((kk * 4 + quad) ^ (lm & 7)) * 8)]);
  };
  auto rdB = [&](int so, int f, int kk) {
    return lds8(&Bs[so + (wc * 64 + f * 16 + lm) * 64 + (((kk * 4 + quad) ^ (lm & 7)) * 8)]);
  };

  // prologue: FIFO = steady-state order: tile0 {B0,B1,A0,A1}; tile1 {B0,B1,A0}
  stgB(0, 0, 0); stgB(0, 1, 0); stgA(0, 0, 0); stgA(0, 1, 0);
  stgB(1, 0, 1); stgB(1, 1, 1); stgA(1, 0, 1);
  asm volatile("s_waitcnt vmcnt(6)" ::: "memory");   // tile0 landed
  __builtin_amdgcn_sched_barrier(0);
  __builtin_amdgcn_s_barrier();

#pragma unroll 2
  for (int t = 0; t < 64; ++t) {
    __builtin_amdgcn_sched_barrier(0);   // keep this tile's reads below the barrier
    const int s = t & 1;
    const int so = s * 8192;
    bf16x8 a[4][2], b[4][2];
    // ---- half 1: reads (kk0 then kk1, pinned); stage A1[t+1]; MFMA kk0 ----
#pragma unroll
    for (int f = 0; f < 4; ++f) { a[f][0] = rdA(so, f, 0); }
#pragma unroll
    for (int f = 0; f < 4; ++f) { b[f][0] = rdB(so, f, 0); }
    __builtin_amdgcn_sched_barrier(0);   // pin: kk0 reads issued first
#pragma unroll
    for (int f = 0; f < 4; ++f) { a[f][1] = rdA(so, f, 1); }
#pragma unroll
    for (int f = 0; f < 4; ++f) { b[f][1] = rdB(so, f, 1); }
    if (t < 63) stgA(s ^ 1, 1, t + 1);
    asm volatile("s_waitcnt lgkmcnt(8)" ::: "memory");   // kk0 frags ready
    __builtin_amdgcn_sched_barrier(0);
    __builtin_amdgcn_s_setprio(1);
#pragma unroll
    for (int mf = 0; mf < 4; ++mf)
#pragma unroll
      for (int nf = 0; nf < 4; ++nf)
        acc[mf][nf] = mfma16(a[mf][0], b[nf][0], acc[mf][nf]);
    __builtin_amdgcn_s_setprio(0);
    asm volatile("s_waitcnt lgkmcnt(0)" ::: "memory");   // all slot-s reads retired
    __builtin_amdgcn_sched_barrier(0);
    __builtin_amdgcn_s_barrier();
    // ---- half 2: stage B0,B1,A0[t+2] into s; MFMA kk1; counted vmcnt ----
    if (t < 62) { stgB(s, 0, t + 2); stgB(s, 1, t + 2); stgA(s, 0, t + 2); }
    __builtin_amdgcn_s_setprio(1);
#pragma unroll
    for (int mf = 0; mf < 4; ++mf)
#pragma unroll
      for (int nf = 0; nf < 4; ++nf)
        acc[mf][nf] = mfma16(a[mf][1], b[nf][1], acc[mf][nf]);
    __builtin_amdgcn_s_setprio(0);
    if (t < 62)       asm volatile("s_waitcnt vmcnt(6)" ::: "memory");
    else if (t == 62) asm volatile("s_waitcnt vmcnt(0)" ::: "memory");
    __builtin_amdgcn_sched_barrier(0);
    __builtin_amdgcn_s_barrier();
  }
}

// ---- fused QKV GEMM + RoPE + layout scatter. XCD-region remap (verified R6). ----
__global__ __launch_bounds__(256, 2) void gemm_qkv8(const unsigned short* __restrict__ A,
                                                    const unsigned short* __restrict__ Bt,
                                                    const void* __restrict__ fcv,
                                                    unsigned short* __restrict__ qo,
                                                    unsigned short* __restrict__ ko,
                                                    unsigned short* __restrict__ vo) {
  __shared__ __align__(16) unsigned short As[2 * 8192];
  __shared__ __align__(16) unsigned short Bs[2 * 8192];
  const int bid = (int)blockIdx.x;                 // 1536 blocks
  const int xcd = bid & 7, idx = bid >> 3;         // idx 0..191
  const int band = idx >> 6;                       // 0..2
  const int rr = idx & 63;                         // 8x8 generation
  const long tileM = (long)((xcd & 3) * 8 + (rr & 7)) * 128;
  const long tileN = (long)((xcd >> 2) * 24 + band * 8 + (rr >> 3)) * 128;
  f32x4 acc[4][4] = {};
  gemm128_loop(A, Bt, As, Bs, tileM, tileN, acc);
  // ---- epilogue: rope + scatter ----
  const int tid = (int)threadIdx.x;
  const int lane = tid & 63, wave = tid >> 6;
  const int wr = wave >> 1, wc = wave & 1;
  const int lm = lane & 15, quad = lane >> 4;
  const int isbf = is_bf16(fcv);
  const int nb = (int)tileN + wc * 64;             // 64-aligned; region uniform per wave
  if (nb < 5120) {                                 // q or k: rope
    const int isk = (nb >= 4096);
    unsigned short* dst = isk ? ko : qo;
    const int hpb = isk ? NKV : NH;
    const int coff = isk ? 4096 : 0;
    const float qs = isk ? 1.0f : 0.08838834764831845f;  // fold softmax scale into q
#pragma unroll
    for (int mf = 0; mf < 4; ++mf)
#pragma unroll
      for (int r = 0; r < 4; ++r) {
        const int m = (int)tileM + wr * 64 + mf * 16 + quad * 4 + r;
        const int b = m >> 11, tq = m & (TSEQ - 1);
#pragma unroll
        for (int nf = 0; nf < 4; ++nf) {
          const int n = nb + nf * 16 + lm;
          float val = acc[mf][nf][r];
          float par = __shfl_xor(val, 1);
          const int ip = (n & 127) >> 1;
          const long fo = (long)tq * 64 + ip;
          float cz, sz;
          if (isbf) {
            const unsigned short* fu = (const unsigned short*)fcv;
            cz = bf2f(fu[fo * 2]); sz = bf2f(fu[fo * 2 + 1]);
          } else {
            float2 cs = ((const float2*)fcv)[fo];
            cz = cs.x; sz = cs.y;
          }
          float out = (n & 1) ? (val * cz + par * sz) : (val * cz - par * sz);
          const int h = (n - coff) >> 7, d = n & 127;
          dst[((long)(b * hpb + h) * TSEQ + tq) * HD + d] = f2bf(out * qs);
        }
      }
  } else {                                         // v: transposed store vT[(b,kvh,d),t]
#pragma unroll
    for (int mf = 0; mf < 4; ++mf)
#pragma unroll
      for (int r = 0; r < 4; ++r) {
        const int m = (int)tileM + wr * 64 + mf * 16 + quad * 4 + r;
        const int b = m >> 11, tq = m & (TSEQ - 1);
#pragma unroll
        for (int nf = 0; nf < 4; ++nf) {
          const int n = nb + nf * 16 + lm;
          const int h = (n - 5120) >> 7, d = n & 127;
          vo[((long)(b * NKV + h) * HD + d) * TSEQ + tq] = f2bf(acc[mf][nf][r]);
        }
      }
  }
}

// ---- wo GEMM: C(4096x4096) = A * Bt^T. XCD region 8M x 16N, 8x8 generations. ----
__global__ __launch_bounds__(256, 2) void gemm_wo8(const unsigned short* __restrict__ A,
                                                   const unsigned short* __restrict__ Bt,
                                                   void* __restrict__ Cv,
                                                   const void* __restrict__ fcv) {
  __shared__ __align__(16) unsigned short As[2 * 8192];
  __shared__ __align__(16) unsigned short Bs[2 * 8192];
  const int bid = (int)blockIdx.x;                 // 1024 blocks
  const int xcd = bid & 7, idx = bid >> 3;         // idx 0..127
  const int band = idx >> 6;                       // 0..1
  const int rr = idx & 63;
  const long tileM = (long)((xcd & 3) * 8 + (rr & 7)) * 128;
  const long tileN = (long)((xcd >> 2) * 16 + band * 8 + (rr >> 3)) * 128;
  f32x4 acc[4][4] = {};
  gemm128_loop(A, Bt, As, Bs, tileM, tileN, acc);
  const int tid = (int)threadIdx.x;
  const int lane = tid & 63, wave = tid >> 6;
  const int wr = wave >> 1, wc = wave & 1;
  const int lm = lane & 15, quad = lane >> 4;
  const int obf = is_bf16(fcv);
  const long N = 4096;
  if (obf) {
    unsigned short* C = (unsigned short*)Cv;
#pragma unroll
    for (int mf = 0; mf < 4; ++mf)
#pragma unroll
      for (int nf = 0; nf < 4; ++nf)
#pragma unroll
        for (int r = 0; r < 4; ++r)
          C[(tileM + wr * 64 + mf * 16 + quad * 4 + r) * N + tileN + wc * 64 + nf * 16 + lm] =
              f2bf(acc[mf][nf][r]);
  } else {
    float* C = (float*)Cv;
#pragma unroll
    for (int mf = 0; mf < 4; ++mf)
#pragma unroll
      for (int nf = 0; nf < 4; ++nf)
#pragma unroll
        for (int r = 0; r < 4; ++r)
          C[(tileM + wr * 64 + mf * 16 + quad * 4 + r) * N + tileN + wc * 64 + nf * 16 + lm] =
              acc[mf][nf][r];
  }
}

// ---- flash attention v5 (verified R9): triple-buffered K/V, one barrier/tile,
// per-wave masked-tile skip, setprio, softmax scale pre-folded into q. ----
__global__ __launch_bounds__(512, 2) void flash_attn(const unsigned short* __restrict__ q,
                                                     const unsigned short* __restrict__ k,
                                                     const unsigned short* __restrict__ vT,
                                                     unsigned short* __restrict__ y) {
  __shared__ unsigned short Ks[3][32 * 128];   // (key, d), chunk-swizzled
  __shared__ unsigned short Vs[3][128 * 32];   // (d, key), chunk-swizzled
  __shared__ unsigned short Pl[8][32 * 40];    // per-wave P (32q x 32k), stride 40
  const int tid = threadIdx.x;
  const int lane = tid & 63, wave = tid >> 6;  // 8 waves
  const int lm = lane & 15, quad = lane >> 4;
  const int bid = (int)blockIdx.x;
  const int halfg = bid >> 8, jj = bid & 255;
  const int qt = jj >> 6, bh = jj & 63;
  const int qi = halfg ? qt : 7 - qt;          // heavy half first
  const int b = bh >> 5, h = bh & 31, kvh = h >> 2;
  const int q0 = qi * 256;
  const unsigned short* Kb = k + (long)(b * NKV + kvh) * TSEQ * HD;
  const unsigned short* Vb = vT + (long)(b * NKV + kvh) * HD * TSEQ;
  const unsigned short* Qb = q + ((long)(b * NH + h) * TSEQ + q0 + wave * 32) * HD;
  bf16x8 qf[2][4];
#pragma unroll
  for (int mi = 0; mi < 2; ++mi)
#pragma unroll
    for (int ks = 0; ks < 4; ++ks)
      qf[mi][ks] = __builtin_bit_cast(bf16x8,
          *(const ushort8v*)(Qb + (mi * 16 + lm) * HD + ks * 32 + quad * 8));
  f32x4 o[2][8] = {};
  float li[2][4] = {};
  const int krow = tid >> 4, kcl = ((tid & 15) ^ (krow & 7)) * 8;       // krow 0..31
  const int vrow = tid >> 2, vcl = ((tid & 3) ^ ((vrow >> 1) & 3)) * 8; // vrow 0..127
  const int ktiles = qi * 8 + 8;
  const int mylast = qi * 8 + wave;            // this wave's diagonal k-tile
  unsigned short* PlW = &Pl[wave][0];

  auto stage = [&](int s2, int t2) {
    gload16(Kb + (long)t2 * 32 * HD + krow * HD + kcl, &Ks[s2][tid * 8]);
    gload16(Vb + t2 * 32 + (long)vrow * TSEQ + vcl, &Vs[s2][tid * 8]);
  };
  // prologue: stage tiles 0,1; drain tile 0 (4 outstanding -> vmcnt(2))
  stage(0, 0); stage(1, 1);
  asm volatile("s_waitcnt vmcnt(2)" ::: "memory");
  __builtin_amdgcn_sched_barrier(0);
  __builtin_amdgcn_s_barrier();

  for (int kt = 0; kt < ktiles; ++kt) {
    const int s = kt % 3;
    if (kt <= mylast) {
      const unsigned short* KsB = Ks[s];
      const unsigned short* VsB = Vs[s];
      f32x4 sc[2][2] = {};
      __builtin_amdgcn_s_setprio(1);
#pragma unroll
      for (int ni = 0; ni < 2; ++ni)
#pragma unroll
        for (int ks = 0; ks < 4; ++ks) {
          bf16x8 kf = lds8(&KsB[(ni * 16 + lm) * 128 + ((ks * 4 + quad) ^ (lm & 7)) * 8]);
          sc[0][ni] = mfma16(qf[0][ks], kf, sc[0][ni]);
          sc[1][ni] = mfma16(qf[1][ks], kf, sc[1][ni]);
        }
      __builtin_amdgcn_s_setprio(0);
      if (kt < mylast) {                       // full tile: no causal compare
#pragma unroll
        for (int mi = 0; mi < 2; ++mi)
#pragma unroll
          for (int r = 0; r < 4; ++r)
#pragma unroll
            for (int ni = 0; ni < 2; ++ni) {
              float p = __expf(sc[mi][ni][r]);
              li[mi][r] += p;
              PlW[(mi * 16 + quad * 4 + r) * 40 + ni * 16 + lm] = f2bf(p);
            }
      } else {                                 // diagonal tile: mask col<=row
#pragma unroll
        for (int mi = 0; mi < 2; ++mi)
#pragma unroll
          for (int r = 0; r < 4; ++r) {
            const int rowo = mi * 16 + quad * 4 + r;
#pragma unroll
            for (int ni = 0; ni < 2; ++ni) {
              const int colo = ni * 16 + lm;
              float p = (colo <= rowo) ? __expf(sc[mi][ni][r]) : 0.f;
              li[mi][r] += p;
              PlW[rowo * 40 + colo] = f2bf(p);
            }
          }
      }
      bf16x8 pf0 = lds8(&PlW[lm * 40 + quad * 8]);
      bf16x8 pf1 = lds8(&PlW[(16 + lm) * 40 + quad * 8]);
      __builtin_amdgcn_s_setprio(1);
#pragma unroll
      for (int db = 0; db < 8; ++db) {
        bf16x8 vf = lds8(&VsB[(db * 16 + lm) * 32 + (quad ^ ((lm >> 1) & 3)) * 8]);
        o[0][db] = mfma16(pf0, vf, o[0][db]);
        o[1][db] = mfma16(pf1, vf, o[1][db]);
      }
      __builtin_amdgcn_s_setprio(0);
    }
    __builtin_amdgcn_sched_barrier(0);
    if (kt + 2 < ktiles) {
      stage((kt + 2) % 3, kt + 2);           // slot last read at tile kt-1
      asm volatile("s_waitcnt vmcnt(2)" ::: "memory");   // tile kt+1 landed
    } else if (kt + 1 < ktiles) {
      asm volatile("s_waitcnt vmcnt(0)" ::: "memory");
    }
    __builtin_amdgcn_sched_barrier(0);
    __builtin_amdgcn_s_barrier();            // single barrier per tile
  }
  float inv[2][4];
#pragma unroll
  for (int mi = 0; mi < 2; ++mi)
#pragma unroll
    for (int r = 0; r < 4; ++r) {
      float l = li[mi][r];
      l += __shfl_xor(l, 1, 16);
      l += __shfl_xor(l, 2, 16);
      l += __shfl_xor(l, 4, 16);
      l += __shfl_xor(l, 8, 16);
      inv[mi][r] = 1.0f / l;
    }
  unsigned short* yo = y + ((long)b * TSEQ + q0 + wave * 32) * DIM + h * 128 + lm;
#pragma unroll
  for (int mi = 0; mi < 2; ++mi)
#pragma unroll
    for (int r = 0; r < 4; ++r) {
      unsigned short* yr = yo + (long)(mi * 16 + quad * 4 + r) * DIM;
#pragma unroll
      for (int db = 0; db < 8; ++db)
        yr[db * 16] = f2bf(o[mi][db][r] * inv[mi][r]);
    }
}

extern "C" void kernel_launch(void* const* d_in, const int* in_sizes, int n_in,
                              void* d_out, int out_size, void* d_ws, size_t ws_size,
                              hipStream_t stream) {
  const void* x  = d_in[0];
  const void* fc = d_in[1];
  const void* wq = d_in[2];
  const void* wk = d_in[3];
  const void* wv = d_in[4];
  const void* wo = d_in[5];
  char* ws = (char*)d_ws;
  unsigned short* xb    = (unsigned short*)(ws + 256);      // 16,777,216 elems (reused as y)
  unsigned short* wqkvT = xb + 16777216L;                   // 25,165,824 elems
  unsigned short* woT   = wqkvT + 25165824L;                // 16,777,216 elems
  unsigned short* qb    = woT + 16777216L;                  // 16,777,216 elems
  unsigned short* kb    = qb + 16777216L;                   //  4,194,304 elems
  unsigned short* vb    = kb + 4194304L;                    //  4,194,304 elems
  unsigned short* yb    = xb;

  prep<<<dim3(26624), dim3(256), 0, stream>>>(x, fc, wq, wk, wv, wo, xb, wqkvT, woT);
  gemm_qkv8<<<dim3(1536), dim3(256), 0, stream>>>(xb, wqkvT, fc, qb, kb, vb);
  flash_attn<<<dim3(512), dim3(512), 0, stream>>>(qb, kb, vb, yb);
  gemm_wo8<<<dim3(1024), dim3(256), 0, stream>>>(yb, woT, d_out, fc);
}